// Round 24
// baseline (722.528 us; speedup 1.0000x reference)
//
#include <hip/hip_runtime.h>
#include <hip/hip_bf16.h>
#include <hip/hip_fp8.h>
#include <math.h>

#define B_      256
#define DA      1024
#define S_      8
#define DK      128
#define NKEYS   100000
#define KMAX    32
#define KTOT    1024            // S_*DK flattened reduction dim
#define BN      128             // n-tile per block (pass_b)
#define BK      64              // k per LDS step
#define NBLK    ((NKEYS + BN - 1) / BN)
#define GB      8               // b-rows per pass_a block
#define ZCH     256             // a-chunk floats
#define NA_BLK  (B_ / GB * S_)  // 256 pass_a blocks
#define NK_BLK  ((S_ * NKEYS) / 16)  // 50000 pass_k blocks
#define KSCALE  16.0f
#define QSCALE  4.0f
#define AK_REP  3               // ATTRIBUTION: in-kernel reps (counter visibility)
#define C_REP   3

typedef __attribute__((ext_vector_type(8))) short short8;
typedef __attribute__((ext_vector_type(4))) float f32x4;

typedef const __attribute__((address_space(1))) unsigned gu32;
typedef __attribute__((address_space(3))) unsigned lu32;
#define GLOAD_LDS16(g, s) __builtin_amdgcn_global_load_lds((gu32*)(g), (lu32*)(s), 16, 0, 0)

__device__ __forceinline__ float bf16_up(short h) {
    union { unsigned u; float f; } cv;
    cv.u = ((unsigned)(unsigned short)h) << 16;
    return cv.f;
}
__device__ __forceinline__ unsigned char f32_to_e4m3(float x) {
    __hip_fp8_e4m3 h(x);
    return (unsigned char)h.__x;
}

// ---------------------------------------------------------------------------
// Fused pass A+K (R21 logic), body repeated AK_REP x for counter visibility
// (pure function of inputs; reps rewrite identical bytes; a-path barrier
// sequence is rep-safe since each g-iteration ends in __syncthreads).
// ---------------------------------------------------------------------------
__global__ __launch_bounds__(256) void pass_ak_kernel(
    const float* __restrict__ z, const float* __restrict__ wq,
    const float* __restrict__ keys, const float* __restrict__ aw,
    float* __restrict__ QT, unsigned char* __restrict__ Q8,
    float* __restrict__ F, unsigned char* __restrict__ K8)
{
    __shared__ float zsh[GB][ZCH];                // 8 KB (a-path only)
    __shared__ double part[2];

    for (int rep = 0; rep < AK_REP; ++rep) {
    if (blockIdx.x < NA_BLK) {
        const int ab = blockIdx.x;
        const int b0 = (ab & (B_ / GB - 1)) * GB;
        const int s  = ab >> 5;
        const int tid = threadIdx.x;
        const int k = tid & 127;
        const bool act = tid < 128;
        const float* wrow = wq + (size_t)(s * DK + k) * DA;
        double acc[GB] = {};

        for (int ch = 0; ch < DA; ch += ZCH) {
            __syncthreads();
            for (int i = tid; i < GB * ZCH; i += 256)
                zsh[i >> 8][i & (ZCH - 1)] =
                    z[(size_t)(b0 + (i >> 8)) * DA + ch + (i & (ZCH - 1))];
            __syncthreads();
            if (act) {
                for (int a = 0; a < ZCH; a += 32) {
                    float4 w[8];
                    #pragma unroll
                    for (int j = 0; j < 8; ++j)
                        w[j] = *reinterpret_cast<const float4*>(wrow + ch + a + 4 * j);
                    #pragma unroll
                    for (int j = 0; j < 8; ++j) {
                        const int aa = a + 4 * j;
                        #pragma unroll
                        for (int g = 0; g < GB; ++g) {
                            acc[g] += (double)w[j].x * (double)zsh[g][aa + 0];
                            acc[g] += (double)w[j].y * (double)zsh[g][aa + 1];
                            acc[g] += (double)w[j].z * (double)zsh[g][aa + 2];
                            acc[g] += (double)w[j].w * (double)zsh[g][aa + 3];
                        }
                    }
                }
            }
        }
        #pragma unroll
        for (int g = 0; g < GB; ++g) {
            double sq = acc[g] * acc[g];
            #pragma unroll
            for (int off = 32; off > 0; off >>= 1) sq += __shfl_down(sq, off);
            if (act && (tid & 63) == 0) part[tid >> 6] = sq;
            __syncthreads();
            const double ss  = part[0] + part[1];
            const double inv = 1.0 / (sqrt(ss) + 1e-8);
            if (act) {
                const float qv = (float)(acc[g] * inv);
                QT[(size_t)(s * DK + k) * B_ + b0 + g] = qv;
                Q8[(size_t)(b0 + g) * KTOT + s * DK + k] = f32_to_e4m3(qv * QSCALE);
            }
            __syncthreads();
        }
    } else {
        float e[S_];
        float mx = aw[0];
        #pragma unroll
        for (int i = 1; i < S_; ++i) mx = fmaxf(mx, aw[i]);
        float se = 0.f;
        #pragma unroll
        for (int i = 0; i < S_; ++i) { e[i] = expf(aw[i] - mx); se += e[i]; }

        const int g = threadIdx.x >> 4, l = threadIdx.x & 15;
        const long long sn = (long long)(blockIdx.x - NA_BLK) * 16 + g;
        const float* row = keys + (size_t)sn * DK + l * 8;
        const float4 r0 = *reinterpret_cast<const float4*>(row + 0);
        const float4 r1 = *reinterpret_cast<const float4*>(row + 4);
        double sq = (double)r0.x * r0.x + (double)r0.y * r0.y +
                    (double)r0.z * r0.z + (double)r0.w * r0.w +
                    (double)r1.x * r1.x + (double)r1.y * r1.y +
                    (double)r1.z * r1.z + (double)r1.w * r1.w;
        #pragma unroll
        for (int off = 1; off < 16; off <<= 1) sq += __shfl_xor(sq, off);
        const int s = (int)(sn / NKEYS);
        const float w = e[s] / se;
        const float f = (float)((double)w / (sqrt(sq) + 1e-8));
        if (l == 0) F[sn] = f;

        const float fs = f * KSCALE;
        const float vv[8] = {r0.x, r0.y, r0.z, r0.w, r1.x, r1.y, r1.z, r1.w};
        unsigned long long pk = 0ull;
        #pragma unroll
        for (int ee = 0; ee < 8; ++ee)
            pk |= (unsigned long long)f32_to_e4m3(vv[ee] * fs) << (8 * ee);
        *reinterpret_cast<unsigned long long*>(K8 + (size_t)sn * DK + l * 8) = pk;
    }
    }  // rep
}

// ---------------------------------------------------------------------------
// Pass B fp8 (R19-verbatim; measured T_b ~= 53us).
// ---------------------------------------------------------------------------
__global__ __launch_bounds__(512) void pass_b_kernel(
    const unsigned char* __restrict__ K8, const unsigned char* __restrict__ Q8,
    __hip_bfloat16* __restrict__ C)
{
    __shared__ __align__(16) char smem[32768];   // A:[0,16K) B0:[16K,24K) B1:[24K,32K)
    const int n0 = blockIdx.x * BN;
    const int tid = threadIdx.x;
    const int w = tid >> 6, l = tid & 63;
    const int ln = l & 15, lk = l >> 4;
    const int wm = w >> 1, wn = w & 1;           // 4M x 2N wave grid
    const int lr = l >> 2;                        // staging row-in-chunk 0..15
    const int gg = (l & 3) * 2;                   // staging dest octet (even)

    f32x4 acc[4][4];
    #pragma unroll
    for (int i = 0; i < 4; ++i)
        #pragma unroll
        for (int j = 0; j < 4; ++j) acc[i][j] = (f32x4){0.f, 0.f, 0.f, 0.f};

    const char* q8 = (const char*)Q8;
    const char* k8 = (const char*)K8;

    auto stage_b = [&](int t) {
        const int kc   = t * BK;
        const int sidx = kc >> 7;
        const int kl   = kc & (DK - 1);
        const int nr   = w * 16 + lr;
        const size_t gn = (size_t)sidx * NKEYS + (n0 + nr);
        const char* g = k8 + gn * DK + kl + ((gg ^ (nr & 6)) << 3);
        GLOAD_LDS16(g, smem + 16384 + (t & 1) * 8192 + w * 1024);
    };

    stage_b(0);

    for (int t = 0; t < 16; ++t) {
        const int kc = t * BK;
        #pragma unroll
        for (int i = 0; i < 2; ++i) {
            const int j  = w + 8 * i;
            const int bq = j * 16 + lr;
            const char* g = q8 + (size_t)bq * KTOT + kc + ((gg ^ (bq & 6)) << 3);
            GLOAD_LDS16(g, smem + j * 1024);
        }
        stage_b(t + 1);
        asm volatile("s_waitcnt vmcnt(1)" ::: "memory");
        __builtin_amdgcn_sched_barrier(0);
        __builtin_amdgcn_s_barrier();
        __builtin_amdgcn_sched_barrier(0);
        const char* bbase = smem + 16384 + (t & 1) * 8192;
        #pragma unroll
        for (int kw = 0; kw < 2; ++kw) {
            const int slot = kw * 4 + lk;
            long af[4], bf[4];
            #pragma unroll
            for (int mi = 0; mi < 4; ++mi) {
                const int r = wm * 64 + mi * 16 + ln;
                af[mi] = *reinterpret_cast<const long*>(smem + r * 64 + ((slot ^ (r & 6)) << 3));
            }
            #pragma unroll
            for (int nf = 0; nf < 4; ++nf) {
                const int nr = wn * 64 + nf * 16 + ln;
                bf[nf] = *reinterpret_cast<const long*>(bbase + nr * 64 + ((slot ^ (nr & 6)) << 3));
            }
            #pragma unroll
            for (int mi = 0; mi < 4; ++mi)
                #pragma unroll
                for (int nf = 0; nf < 4; ++nf)
                    acc[mi][nf] = __builtin_amdgcn_mfma_f32_16x16x32_fp8_fp8(
                        af[mi], bf[nf], acc[mi][nf], 0, 0, 0);
        }
        __builtin_amdgcn_s_barrier();
    }
    asm volatile("s_waitcnt vmcnt(0)" ::: "memory");

    #pragma unroll
    for (int mi = 0; mi < 4; ++mi) {
        #pragma unroll
        for (int nf = 0; nf < 4; ++nf) {
            const int n = n0 + wn * 64 + nf * 16 + ln;
            if (n < NKEYS) {
                #pragma unroll
                for (int r = 0; r < 4; ++r) {
                    const int bq = wm * 64 + mi * 16 + lk * 4 + r;
                    C[(size_t)bq * NKEYS + n] = __float2bfloat16(acc[mi][nf][r]);
                }
            }
        }
    }
}

// ---------------------------------------------------------------------------
// Pass C v10 (R23 logic), body repeated C_REP x for counter visibility.
// Rep-safety: threads >=64 racing into rep r+1 block at its first
// __syncthreads (stats) until wave 0 exits rep r's top-32; rep r+1's compact
// (which overwrites cidx/cval) cannot start before that barrier.
// ---------------------------------------------------------------------------
#define MAXC 2048
#define NV8 12500
#define NSS (NV8 / 8)
#define CTH 512

__global__ __launch_bounds__(512) void pass_c_kernel(
    const __hip_bfloat16* __restrict__ C, const float* __restrict__ keys,
    const float* __restrict__ QT, const float* __restrict__ F,
    const float* __restrict__ tau_p, const float* __restrict__ lam_p,
    const unsigned char* __restrict__ warm_p, float* __restrict__ out)
{
    const int b = blockIdx.x, tid = threadIdx.x;
    __shared__ float redA[8], redB[8];
    __shared__ double cval[MAXC];
    __shared__ int cidx[MAXC];
    __shared__ int cnt;
    __shared__ float sh_stat[2];
    __shared__ double topv[KMAX];
    __shared__ int topi[KMAX];

    const __hip_bfloat16* crow = C + (size_t)b * NKEYS;

    for (int rep = 0; rep < C_REP; ++rep) {
    // ---- stats: subsampled pass (every 8th short8), 2-way ILP ----
    float sm = 0.f, sq = 0.f;
    for (int ii = tid; ii < NSS; ii += 2 * CTH) {
        const short8 v0 = *reinterpret_cast<const short8*>(crow + (size_t)ii * 64);
        const bool ok1 = (ii + CTH) < NSS;
        short8 v1 = v0;
        if (ok1) v1 = *reinterpret_cast<const short8*>(crow + (size_t)(ii + CTH) * 64);
        #pragma unroll
        for (int e = 0; e < 8; ++e) {
            const float v = bf16_up(v0[e]);
            sm += v; sq += v * v;
        }
        if (ok1) {
            #pragma unroll
            for (int e = 0; e < 8; ++e) {
                const float v = bf16_up(v1[e]);
                sm += v; sq += v * v;
            }
        }
    }
    #pragma unroll
    for (int off = 32; off > 0; off >>= 1) {
        sm += __shfl_down(sm, off);
        sq += __shfl_down(sq, off);
    }
    __syncthreads();                              // rep-boundary guard
    if ((tid & 63) == 0) { redA[tid >> 6] = sm; redB[tid >> 6] = sq; }
    __syncthreads();
    if (tid == 0) {
        float S1 = 0.f, S2 = 0.f;
        #pragma unroll
        for (int i = 0; i < 8; ++i) { S1 += redA[i]; S2 += redB[i]; }
        const float nsv = (float)(NSS * 8);
        const float mu = S1 / nsv;
        sh_stat[0] = mu;
        sh_stat[1] = sqrtf(fmaxf(S2 / nsv - mu * mu, 1e-12f));
    }
    __syncthreads();
    const float mu = sh_stat[0], sg = sh_stat[1];

    // ---- compact candidates: analytic threshold + ladder; 4-way ILP ----
    int m = 0;
    #pragma unroll 1
    for (int attempt = 0; attempt < 4; ++attempt) {
        const float ct = (attempt == 0) ? (mu + 3.0f * sg)
                       : (attempt == 1) ? (mu + 2.5f * sg)
                       : (attempt == 2) ? mu : -1e9f;
        __syncthreads();
        if (tid == 0) cnt = 0;
        __syncthreads();
        int i = tid;
        for (; i + 3 * CTH < NV8; i += 4 * CTH) {
            const short8 v0 = *reinterpret_cast<const short8*>(crow + (size_t)(i          ) * 8);
            const short8 v1 = *reinterpret_cast<const short8*>(crow + (size_t)(i +     CTH) * 8);
            const short8 v2 = *reinterpret_cast<const short8*>(crow + (size_t)(i + 2 * CTH) * 8);
            const short8 v3 = *reinterpret_cast<const short8*>(crow + (size_t)(i + 3 * CTH) * 8);
            #pragma unroll
            for (int e = 0; e < 8; ++e)
                if (bf16_up(v0[e]) >= ct) {
                    const int p = atomicAdd(&cnt, 1);
                    if (p < MAXC) cidx[p] = i * 8 + e;
                }
            #pragma unroll
            for (int e = 0; e < 8; ++e)
                if (bf16_up(v1[e]) >= ct) {
                    const int p = atomicAdd(&cnt, 1);
                    if (p < MAXC) cidx[p] = (i + CTH) * 8 + e;
                }
            #pragma unroll
            for (int e = 0; e < 8; ++e)
                if (bf16_up(v2[e]) >= ct) {
                    const int p = atomicAdd(&cnt, 1);
                    if (p < MAXC) cidx[p] = (i + 2 * CTH) * 8 + e;
                }
            #pragma unroll
            for (int e = 0; e < 8; ++e)
                if (bf16_up(v3[e]) >= ct) {
                    const int p = atomicAdd(&cnt, 1);
                    if (p < MAXC) cidx[p] = (i + 3 * CTH) * 8 + e;
                }
        }
        for (; i < NV8; i += CTH) {
            const short8 v8 = *reinterpret_cast<const short8*>(crow + (size_t)i * 8);
            #pragma unroll
            for (int e = 0; e < 8; ++e)
                if (bf16_up(v8[e]) >= ct) {
                    const int p = atomicAdd(&cnt, 1);
                    if (p < MAXC) cidx[p] = i * 8 + e;
                }
        }
        __syncthreads();
        m = min(cnt, MAXC);
        if (m >= KMAX) break;
    }

    // ---- fp64 exact re-rank, one candidate per wave (8 waves) ----
    const int wave = tid >> 6, lane = tid & 63;
    const int si = lane >> 3, kg = lane & 7;
    for (int c = wave; c < m; c += 8) {
        const int n = cidx[c];
        const float f = F[(size_t)si * NKEYS + n];
        const float* krow = keys + ((size_t)si * NKEYS + n) * DK + kg * 16;
        const float* qb = QT + (size_t)(si * DK + kg * 16) * B_ + b;
        double acc = 0.0;
        #pragma unroll
        for (int jj = 0; jj < 4; ++jj) {
            const float4 kv = *reinterpret_cast<const float4*>(krow + jj * 4);
            acc += (double)qb[(size_t)(jj * 4 + 0) * B_] * ((double)kv.x * (double)f);
            acc += (double)qb[(size_t)(jj * 4 + 1) * B_] * ((double)kv.y * (double)f);
            acc += (double)qb[(size_t)(jj * 4 + 2) * B_] * ((double)kv.z * (double)f);
            acc += (double)qb[(size_t)(jj * 4 + 3) * B_] * ((double)kv.w * (double)f);
        }
        #pragma unroll
        for (int off = 1; off < 64; off <<= 1) acc += __shfl_xor(acc, off);
        if (lane == 0) cval[c] = acc;
    }
    __syncthreads();

    // ---- single-wave exact top-32 (desc value, ties -> asc index) ----
    if (tid < 64) {
        for (int r = 0; r < KMAX; ++r) {
            double bv = -1e300; int bi = 0x7fffffff; int bp = -1;
            for (int c = tid; c < m; c += 64) {
                const double v = cval[c]; const int ix = cidx[c];
                if (v > bv || (v == bv && ix < bi)) { bv = v; bi = ix; bp = c; }
            }
            #pragma unroll
            for (int off = 32; off > 0; off >>= 1) {
                const double ov = __shfl_xor(bv, off);
                const int oi = __shfl_xor(bi, off);
                const int op = __shfl_xor(bp, off);
                if (ov > bv || (ov == bv && oi < bi)) { bv = ov; bi = oi; bp = op; }
            }
            if (tid == 0) { topv[r] = bv; topi[r] = bi; if (bp >= 0) cval[bp] = -1e301; }
        }
        if (tid == 0) {
            const float lamv = lam_p[0];
            const float tauv = tau_p[0];
            const bool warm = warm_p[0] != 0;
            float al[KMAX];
            float ssum = 0.f;
            if (warm) {
                const float x0 = (float)topv[0] / 0.1f;
                for (int i = 0; i < KMAX; ++i) {
                    const float e = expf((float)topv[i] / 0.1f - x0);
                    al[i] = e; ssum += e;
                }
            } else {
                for (int i = 0; i < KMAX; ++i) {
                    const float v = (float)topv[i];
                    const float g = 1.0f / (1.0f + expf(-(lamv * (v - tauv))));
                    const float rr = g * expf(v / 0.1f);
                    al[i] = rr; ssum += rr;
                }
            }
            for (int i = 0; i < KMAX; ++i) {
                out[b * KMAX + i] = al[i] / ssum;
                out[B_ * KMAX + b * KMAX + i] = (float)topi[i];
            }
        }
    }
    }  // rep
}

// ---------------------------------------------------------------------------
extern "C" void kernel_launch(void* const* d_in, const int* in_sizes, int n_in,
                              void* d_out, int out_size, void* d_ws, size_t ws_size,
                              hipStream_t stream) {
    const float* z    = (const float*)d_in[0];
    const float* keys = (const float*)d_in[1];
    const float* wq   = (const float*)d_in[2];
    const float* aw   = (const float*)d_in[3];
    const float* tau  = (const float*)d_in[4];
    const float* lam  = (const float*)d_in[5];
    const unsigned char* warm = (const unsigned char*)d_in[6];
    float* out = (float*)d_out;

    char* ws = (char*)d_ws;
    float* QT           = (float*)ws;                          // @0       1.0 MB
    float* F            = (float*)(ws + (1 << 20));            // @1MB     3.2 MB
    unsigned char* Q8   = (unsigned char*)(ws + (8 << 20));    // @8MB     0.25 MB
    unsigned char* K8   = (unsigned char*)(ws + (16 << 20));   // @16MB  102.4 MB
    __hip_bfloat16* C   = (__hip_bfloat16*)(ws + ((size_t)232 << 20)); // @232MB 51.2 MB

    pass_ak_kernel<<<dim3(NA_BLK + NK_BLK), 256, 0, stream>>>(z, wq, keys, aw, QT, Q8, F, K8);
    pass_b_kernel<<<dim3(NBLK), 512, 0, stream>>>(K8, Q8, C);
    pass_c_kernel<<<dim3(B_), 512, 0, stream>>>(C, keys, QT, F, tau, lam, warm, out);
}

// Round 25
// 279.314 us; speedup vs baseline: 2.5868x; 2.5868x over previous
//
#include <hip/hip_runtime.h>
#include <hip/hip_bf16.h>
#include <hip/hip_fp8.h>
#include <math.h>

#define B_      256
#define DA      1024
#define S_      8
#define DK      128
#define NKEYS   100000
#define KMAX    32
#define KTOT    1024            // S_*DK flattened reduction dim
#define BN      128             // n-tile per block (pass_b)
#define BK      64              // k per LDS step
#define NBLK    ((NKEYS + BN - 1) / BN)
#define GB      8               // b-rows per pass_a block
#define ZCH     256             // a-chunk floats
#define NA_BLK  (B_ / GB * S_)  // 256 pass_a blocks
#define NK_BLK  ((S_ * NKEYS) / 16)  // 50000 pass_k blocks
#define BLK_PER_ASPECT (NKEYS / 16)  // 6250 (exact; NKEYS%16==0)
#define KSCALE  16.0f
#define QSCALE  4.0f

typedef __attribute__((ext_vector_type(8))) short short8;
typedef __attribute__((ext_vector_type(4))) float f32x4;

typedef const __attribute__((address_space(1))) unsigned gu32;
typedef __attribute__((address_space(3))) unsigned lu32;
#define GLOAD_LDS16(g, s) __builtin_amdgcn_global_load_lds((gu32*)(g), (lu32*)(s), 16, 0, 0)

__device__ __forceinline__ float bf16_up(short h) {
    union { unsigned u; float f; } cv;
    cv.u = ((unsigned)(unsigned short)h) << 16;
    return cv.f;
}
__device__ __forceinline__ unsigned char f32_to_e4m3(float x) {
    __hip_fp8_e4m3 h(x);
    return (unsigned char)h.__x;
}

// ---------------------------------------------------------------------------
// Setup: softmax(aspect_weights) computed ONCE (same op order as the old
// per-thread code -> identical fp32 values -> F bit-identical downstream).
// ---------------------------------------------------------------------------
__global__ void pass_w_kernel(const float* __restrict__ aw, float* __restrict__ W8)
{
    if (threadIdx.x == 0 && blockIdx.x == 0) {
        float mx = aw[0];
        #pragma unroll
        for (int i = 1; i < S_; ++i) mx = fmaxf(mx, aw[i]);
        float e[S_]; float se = 0.f;
        #pragma unroll
        for (int i = 0; i < S_; ++i) { e[i] = expf(aw[i] - mx); se += e[i]; }
        #pragma unroll
        for (int i = 0; i < S_; ++i) W8[i] = e[i] / se;
    }
}

// ---------------------------------------------------------------------------
// Fused pass A+K. a-path: R23-verbatim (QT bit-critical). k-path VALU diet
// (R24 PMC: VALUBusy 85%): softmax hoisted to W8 (no 8x expf/thread),
// aspect via int32 magic-div of block index (no int64 div), fp8 pack via
// hardware v_cvt_pk_fp8_f32 (no ctor calls, no 64-bit or/shift chain).
// F values bit-identical; K8 bytes equal up to cvt rounding boundaries
// (output invariant via candidate-superset + fp64 re-rank).
// ---------------------------------------------------------------------------
__global__ __launch_bounds__(256) void pass_ak_kernel(
    const float* __restrict__ z, const float* __restrict__ wq,
    const float* __restrict__ keys, const float* __restrict__ W8,
    float* __restrict__ QT, unsigned char* __restrict__ Q8,
    float* __restrict__ F, unsigned char* __restrict__ K8)
{
    __shared__ float zsh[GB][ZCH];                // 8 KB (a-path only)
    __shared__ double part[2];

    if (blockIdx.x < NA_BLK) {
        const int ab = blockIdx.x;
        const int b0 = (ab & (B_ / GB - 1)) * GB;
        const int s  = ab >> 5;
        const int tid = threadIdx.x;
        const int k = tid & 127;
        const bool act = tid < 128;
        const float* wrow = wq + (size_t)(s * DK + k) * DA;
        double acc[GB] = {};

        for (int ch = 0; ch < DA; ch += ZCH) {
            __syncthreads();
            for (int i = tid; i < GB * ZCH; i += 256)
                zsh[i >> 8][i & (ZCH - 1)] =
                    z[(size_t)(b0 + (i >> 8)) * DA + ch + (i & (ZCH - 1))];
            __syncthreads();
            if (act) {
                for (int a = 0; a < ZCH; a += 32) {
                    float4 w[8];
                    #pragma unroll
                    for (int j = 0; j < 8; ++j)
                        w[j] = *reinterpret_cast<const float4*>(wrow + ch + a + 4 * j);
                    #pragma unroll
                    for (int j = 0; j < 8; ++j) {
                        const int aa = a + 4 * j;
                        #pragma unroll
                        for (int g = 0; g < GB; ++g) {
                            acc[g] += (double)w[j].x * (double)zsh[g][aa + 0];
                            acc[g] += (double)w[j].y * (double)zsh[g][aa + 1];
                            acc[g] += (double)w[j].z * (double)zsh[g][aa + 2];
                            acc[g] += (double)w[j].w * (double)zsh[g][aa + 3];
                        }
                    }
                }
            }
        }
        #pragma unroll
        for (int g = 0; g < GB; ++g) {
            double sq = acc[g] * acc[g];
            #pragma unroll
            for (int off = 32; off > 0; off >>= 1) sq += __shfl_down(sq, off);
            if (act && (tid & 63) == 0) part[tid >> 6] = sq;
            __syncthreads();
            const double ss  = part[0] + part[1];
            const double inv = 1.0 / (sqrt(ss) + 1e-8);
            if (act) {
                const float qv = (float)(acc[g] * inv);
                QT[(size_t)(s * DK + k) * B_ + b0 + g] = qv;
                Q8[(size_t)(b0 + g) * KTOT + s * DK + k] = f32_to_e4m3(qv * QSCALE);
            }
            __syncthreads();
        }
    } else {
        const int brel = blockIdx.x - NA_BLK;
        const int g = threadIdx.x >> 4, l = threadIdx.x & 15;
        const int s = brel / BLK_PER_ASPECT;      // uniform; int32 magic-div
        const long long sn = (long long)brel * 16 + g;
        const float* row = keys + (size_t)sn * DK + l * 8;
        const float4 r0 = *reinterpret_cast<const float4*>(row + 0);
        const float4 r1 = *reinterpret_cast<const float4*>(row + 4);
        double sq = (double)r0.x * r0.x + (double)r0.y * r0.y +
                    (double)r0.z * r0.z + (double)r0.w * r0.w +
                    (double)r1.x * r1.x + (double)r1.y * r1.y +
                    (double)r1.z * r1.z + (double)r1.w * r1.w;
        #pragma unroll
        for (int off = 1; off < 16; off <<= 1) sq += __shfl_xor(sq, off);
        const float w = W8[s];
        const float f = (float)((double)w / (sqrt(sq) + 1e-8));
        if (l == 0) F[sn] = f;

        const float fs = f * KSCALE;
        int lo = 0, hi = 0;
        lo = __builtin_amdgcn_cvt_pk_fp8_f32(r0.x * fs, r0.y * fs, lo, false);
        lo = __builtin_amdgcn_cvt_pk_fp8_f32(r0.z * fs, r0.w * fs, lo, true);
        hi = __builtin_amdgcn_cvt_pk_fp8_f32(r1.x * fs, r1.y * fs, hi, false);
        hi = __builtin_amdgcn_cvt_pk_fp8_f32(r1.z * fs, r1.w * fs, hi, true);
        const unsigned long long pk =
            ((unsigned long long)(unsigned)hi << 32) | (unsigned)lo;
        *reinterpret_cast<unsigned long long*>(K8 + (size_t)sn * DK + l * 8) = pk;
    }
}

// ---------------------------------------------------------------------------
// Pass B fp8 (R19-verbatim; measured T_b ~= 53us).
// ---------------------------------------------------------------------------
__global__ __launch_bounds__(512) void pass_b_kernel(
    const unsigned char* __restrict__ K8, const unsigned char* __restrict__ Q8,
    __hip_bfloat16* __restrict__ C)
{
    __shared__ __align__(16) char smem[32768];   // A:[0,16K) B0:[16K,24K) B1:[24K,32K)
    const int n0 = blockIdx.x * BN;
    const int tid = threadIdx.x;
    const int w = tid >> 6, l = tid & 63;
    const int ln = l & 15, lk = l >> 4;
    const int wm = w >> 1, wn = w & 1;           // 4M x 2N wave grid
    const int lr = l >> 2;                        // staging row-in-chunk 0..15
    const int gg = (l & 3) * 2;                   // staging dest octet (even)

    f32x4 acc[4][4];
    #pragma unroll
    for (int i = 0; i < 4; ++i)
        #pragma unroll
        for (int j = 0; j < 4; ++j) acc[i][j] = (f32x4){0.f, 0.f, 0.f, 0.f};

    const char* q8 = (const char*)Q8;
    const char* k8 = (const char*)K8;

    auto stage_b = [&](int t) {
        const int kc   = t * BK;
        const int sidx = kc >> 7;
        const int kl   = kc & (DK - 1);
        const int nr   = w * 16 + lr;
        const size_t gn = (size_t)sidx * NKEYS + (n0 + nr);
        const char* g = k8 + gn * DK + kl + ((gg ^ (nr & 6)) << 3);
        GLOAD_LDS16(g, smem + 16384 + (t & 1) * 8192 + w * 1024);
    };

    stage_b(0);

    for (int t = 0; t < 16; ++t) {
        const int kc = t * BK;
        #pragma unroll
        for (int i = 0; i < 2; ++i) {
            const int j  = w + 8 * i;
            const int bq = j * 16 + lr;
            const char* g = q8 + (size_t)bq * KTOT + kc + ((gg ^ (bq & 6)) << 3);
            GLOAD_LDS16(g, smem + j * 1024);
        }
        stage_b(t + 1);
        asm volatile("s_waitcnt vmcnt(1)" ::: "memory");
        __builtin_amdgcn_sched_barrier(0);
        __builtin_amdgcn_s_barrier();
        __builtin_amdgcn_sched_barrier(0);
        const char* bbase = smem + 16384 + (t & 1) * 8192;
        #pragma unroll
        for (int kw = 0; kw < 2; ++kw) {
            const int slot = kw * 4 + lk;
            long af[4], bf[4];
            #pragma unroll
            for (int mi = 0; mi < 4; ++mi) {
                const int r = wm * 64 + mi * 16 + ln;
                af[mi] = *reinterpret_cast<const long*>(smem + r * 64 + ((slot ^ (r & 6)) << 3));
            }
            #pragma unroll
            for (int nf = 0; nf < 4; ++nf) {
                const int nr = wn * 64 + nf * 16 + ln;
                bf[nf] = *reinterpret_cast<const long*>(bbase + nr * 64 + ((slot ^ (nr & 6)) << 3));
            }
            #pragma unroll
            for (int mi = 0; mi < 4; ++mi)
                #pragma unroll
                for (int nf = 0; nf < 4; ++nf)
                    acc[mi][nf] = __builtin_amdgcn_mfma_f32_16x16x32_fp8_fp8(
                        af[mi], bf[nf], acc[mi][nf], 0, 0, 0);
        }
        __builtin_amdgcn_s_barrier();
    }
    asm volatile("s_waitcnt vmcnt(0)" ::: "memory");

    #pragma unroll
    for (int mi = 0; mi < 4; ++mi) {
        #pragma unroll
        for (int nf = 0; nf < 4; ++nf) {
            const int n = n0 + wn * 64 + nf * 16 + ln;
            if (n < NKEYS) {
                #pragma unroll
                for (int r = 0; r < 4; ++r) {
                    const int bq = wm * 64 + mi * 16 + lk * 4 + r;
                    C[(size_t)bq * NKEYS + n] = __float2bfloat16(acc[mi][nf][r]);
                }
            }
        }
    }
}

// ---------------------------------------------------------------------------
// Pass C v10 (R23-verbatim).
// ---------------------------------------------------------------------------
#define MAXC 2048
#define NV8 12500
#define NSS (NV8 / 8)
#define CTH 512

__global__ __launch_bounds__(512) void pass_c_kernel(
    const __hip_bfloat16* __restrict__ C, const float* __restrict__ keys,
    const float* __restrict__ QT, const float* __restrict__ F,
    const float* __restrict__ tau_p, const float* __restrict__ lam_p,
    const unsigned char* __restrict__ warm_p, float* __restrict__ out)
{
    const int b = blockIdx.x, tid = threadIdx.x;
    __shared__ float redA[8], redB[8];
    __shared__ double cval[MAXC];
    __shared__ int cidx[MAXC];
    __shared__ int cnt;
    __shared__ float sh_stat[2];
    __shared__ double topv[KMAX];
    __shared__ int topi[KMAX];

    const __hip_bfloat16* crow = C + (size_t)b * NKEYS;

    float sm = 0.f, sq = 0.f;
    for (int ii = tid; ii < NSS; ii += 2 * CTH) {
        const short8 v0 = *reinterpret_cast<const short8*>(crow + (size_t)ii * 64);
        const bool ok1 = (ii + CTH) < NSS;
        short8 v1 = v0;
        if (ok1) v1 = *reinterpret_cast<const short8*>(crow + (size_t)(ii + CTH) * 64);
        #pragma unroll
        for (int e = 0; e < 8; ++e) {
            const float v = bf16_up(v0[e]);
            sm += v; sq += v * v;
        }
        if (ok1) {
            #pragma unroll
            for (int e = 0; e < 8; ++e) {
                const float v = bf16_up(v1[e]);
                sm += v; sq += v * v;
            }
        }
    }
    #pragma unroll
    for (int off = 32; off > 0; off >>= 1) {
        sm += __shfl_down(sm, off);
        sq += __shfl_down(sq, off);
    }
    if ((tid & 63) == 0) { redA[tid >> 6] = sm; redB[tid >> 6] = sq; }
    __syncthreads();
    if (tid == 0) {
        float S1 = 0.f, S2 = 0.f;
        #pragma unroll
        for (int i = 0; i < 8; ++i) { S1 += redA[i]; S2 += redB[i]; }
        const float nsv = (float)(NSS * 8);
        const float mu = S1 / nsv;
        sh_stat[0] = mu;
        sh_stat[1] = sqrtf(fmaxf(S2 / nsv - mu * mu, 1e-12f));
    }
    __syncthreads();
    const float mu = sh_stat[0], sg = sh_stat[1];

    int m = 0;
    #pragma unroll 1
    for (int attempt = 0; attempt < 4; ++attempt) {
        const float ct = (attempt == 0) ? (mu + 3.0f * sg)
                       : (attempt == 1) ? (mu + 2.5f * sg)
                       : (attempt == 2) ? mu : -1e9f;
        __syncthreads();
        if (tid == 0) cnt = 0;
        __syncthreads();
        int i = tid;
        for (; i + 3 * CTH < NV8; i += 4 * CTH) {
            const short8 v0 = *reinterpret_cast<const short8*>(crow + (size_t)(i          ) * 8);
            const short8 v1 = *reinterpret_cast<const short8*>(crow + (size_t)(i +     CTH) * 8);
            const short8 v2 = *reinterpret_cast<const short8*>(crow + (size_t)(i + 2 * CTH) * 8);
            const short8 v3 = *reinterpret_cast<const short8*>(crow + (size_t)(i + 3 * CTH) * 8);
            #pragma unroll
            for (int e = 0; e < 8; ++e)
                if (bf16_up(v0[e]) >= ct) {
                    const int p = atomicAdd(&cnt, 1);
                    if (p < MAXC) cidx[p] = i * 8 + e;
                }
            #pragma unroll
            for (int e = 0; e < 8; ++e)
                if (bf16_up(v1[e]) >= ct) {
                    const int p = atomicAdd(&cnt, 1);
                    if (p < MAXC) cidx[p] = (i + CTH) * 8 + e;
                }
            #pragma unroll
            for (int e = 0; e < 8; ++e)
                if (bf16_up(v2[e]) >= ct) {
                    const int p = atomicAdd(&cnt, 1);
                    if (p < MAXC) cidx[p] = (i + 2 * CTH) * 8 + e;
                }
            #pragma unroll
            for (int e = 0; e < 8; ++e)
                if (bf16_up(v3[e]) >= ct) {
                    const int p = atomicAdd(&cnt, 1);
                    if (p < MAXC) cidx[p] = (i + 3 * CTH) * 8 + e;
                }
        }
        for (; i < NV8; i += CTH) {
            const short8 v8 = *reinterpret_cast<const short8*>(crow + (size_t)i * 8);
            #pragma unroll
            for (int e = 0; e < 8; ++e)
                if (bf16_up(v8[e]) >= ct) {
                    const int p = atomicAdd(&cnt, 1);
                    if (p < MAXC) cidx[p] = i * 8 + e;
                }
        }
        __syncthreads();
        m = min(cnt, MAXC);
        if (m >= KMAX) break;
    }

    const int wave = tid >> 6, lane = tid & 63;
    const int si = lane >> 3, kg = lane & 7;
    for (int c = wave; c < m; c += 8) {
        const int n = cidx[c];
        const float f = F[(size_t)si * NKEYS + n];
        const float* krow = keys + ((size_t)si * NKEYS + n) * DK + kg * 16;
        const float* qb = QT + (size_t)(si * DK + kg * 16) * B_ + b;
        double acc = 0.0;
        #pragma unroll
        for (int jj = 0; jj < 4; ++jj) {
            const float4 kv = *reinterpret_cast<const float4*>(krow + jj * 4);
            acc += (double)qb[(size_t)(jj * 4 + 0) * B_] * ((double)kv.x * (double)f);
            acc += (double)qb[(size_t)(jj * 4 + 1) * B_] * ((double)kv.y * (double)f);
            acc += (double)qb[(size_t)(jj * 4 + 2) * B_] * ((double)kv.z * (double)f);
            acc += (double)qb[(size_t)(jj * 4 + 3) * B_] * ((double)kv.w * (double)f);
        }
        #pragma unroll
        for (int off = 1; off < 64; off <<= 1) acc += __shfl_xor(acc, off);
        if (lane == 0) cval[c] = acc;
    }
    __syncthreads();

    if (tid < 64) {
        for (int r = 0; r < KMAX; ++r) {
            double bv = -1e300; int bi = 0x7fffffff; int bp = -1;
            for (int c = tid; c < m; c += 64) {
                const double v = cval[c]; const int ix = cidx[c];
                if (v > bv || (v == bv && ix < bi)) { bv = v; bi = ix; bp = c; }
            }
            #pragma unroll
            for (int off = 32; off > 0; off >>= 1) {
                const double ov = __shfl_xor(bv, off);
                const int oi = __shfl_xor(bi, off);
                const int op = __shfl_xor(bp, off);
                if (ov > bv || (ov == bv && oi < bi)) { bv = ov; bi = oi; bp = op; }
            }
            if (tid == 0) { topv[r] = bv; topi[r] = bi; if (bp >= 0) cval[bp] = -1e301; }
        }
        if (tid == 0) {
            const float lamv = lam_p[0];
            const float tauv = tau_p[0];
            const bool warm = warm_p[0] != 0;
            float al[KMAX];
            float ssum = 0.f;
            if (warm) {
                const float x0 = (float)topv[0] / 0.1f;
                for (int i = 0; i < KMAX; ++i) {
                    const float e = expf((float)topv[i] / 0.1f - x0);
                    al[i] = e; ssum += e;
                }
            } else {
                for (int i = 0; i < KMAX; ++i) {
                    const float v = (float)topv[i];
                    const float g = 1.0f / (1.0f + expf(-(lamv * (v - tauv))));
                    const float rr = g * expf(v / 0.1f);
                    al[i] = rr; ssum += rr;
                }
            }
            for (int i = 0; i < KMAX; ++i) {
                out[b * KMAX + i] = al[i] / ssum;
                out[B_ * KMAX + b * KMAX + i] = (float)topi[i];
            }
        }
    }
}

// ---------------------------------------------------------------------------
extern "C" void kernel_launch(void* const* d_in, const int* in_sizes, int n_in,
                              void* d_out, int out_size, void* d_ws, size_t ws_size,
                              hipStream_t stream) {
    const float* z    = (const float*)d_in[0];
    const float* keys = (const float*)d_in[1];
    const float* wq   = (const float*)d_in[2];
    const float* aw   = (const float*)d_in[3];
    const float* tau  = (const float*)d_in[4];
    const float* lam  = (const float*)d_in[5];
    const unsigned char* warm = (const unsigned char*)d_in[6];
    float* out = (float*)d_out;

    char* ws = (char*)d_ws;
    float* QT           = (float*)ws;                          // @0       1.0 MB
    float* F            = (float*)(ws + (1 << 20));            // @1MB     3.2 MB
    float* W8           = (float*)(ws + (5 << 20));            // @5MB     32 B
    unsigned char* Q8   = (unsigned char*)(ws + (8 << 20));    // @8MB     0.25 MB
    unsigned char* K8   = (unsigned char*)(ws + (16 << 20));   // @16MB  102.4 MB
    __hip_bfloat16* C   = (__hip_bfloat16*)(ws + ((size_t)232 << 20)); // @232MB 51.2 MB

    pass_w_kernel<<<dim3(1), 64, 0, stream>>>(aw, W8);
    pass_ak_kernel<<<dim3(NA_BLK + NK_BLK), 256, 0, stream>>>(z, wq, keys, W8, QT, Q8, F, K8);
    pass_b_kernel<<<dim3(NBLK), 512, 0, stream>>>(K8, Q8, C);
    pass_c_kernel<<<dim3(B_), 512, 0, stream>>>(C, keys, QT, F, tau, lam, warm, out);
}